// Round 8
// baseline (1663.374 us; speedup 1.0000x reference)
//
#include <hip/hip_runtime.h>
#include <hip/hip_bf16.h>
#include <stdint.h>

// GraphSAGE layer, N=16384, F_IN=F_OUT=256.
// out = (adj@ (x@W1))/deg + x@W2 + bias
//   P0: bitpack adj (1.07 GB int32 -> 32 MB bits) + deg[m] via ballot/popcount
//   K0: WT[n][k] (bf16)  = transpose of [W1|W2]
//   K1: yT[n][m] (bf16)  = (x@W1)^T ;  z[m][n] (f32) = x@W2 + bias
//   K2 v8: v7's tri-buffered raw-barrier MFMA loop, but A sourced from BITS
//          (u32/row/iter, L1-resident; 4 bits -> bf16x4 in ~6 VALU). The
//          900-cyc HBM adj chain is gone from the K-loop; only B (L2/L3)
//          remains in the vmcnt window.
//   K3: out = (p0+p1)/deg + z

typedef short bf16x8 __attribute__((ext_vector_type(8)));
typedef float f32x4  __attribute__((ext_vector_type(4)));

__device__ __forceinline__ uint32_t pack_bf16_rne(float lo, float hi) {
    uint32_t ul = __float_as_uint(lo);
    uint32_t uh = __float_as_uint(hi);
    ul = (ul + 0x7fffu + ((ul >> 16) & 1u)) >> 16;
    uh = (uh + 0x7fffu + ((uh >> 16) & 1u)) >> 16;
    return ul | (uh << 16);
}

__device__ __forceinline__ void gload_lds16(const void* g, void* l) {
    __builtin_amdgcn_global_load_lds(
        (__attribute__((address_space(1))) void*)g,
        (__attribute__((address_space(3))) void*)l, 16, 0, 0);
}

// ---------------- P0: bitpack adj rows + degree
// grid 16384 (1 row/block), 256 threads (4 waves). Wave w ballots 64 ints;
// 64 iters cover the 16384-int row. Pure coalesced stream at fill-rate.
__global__ __launch_bounds__(256) void k_bitpack(const int* __restrict__ adj,
                                                 unsigned long long* __restrict__ bits,
                                                 int* __restrict__ deg) {
    __shared__ int ds[4];
    const int row = blockIdx.x, t = threadIdx.x, lane = t & 63, w = t >> 6;
    const int* p = adj + (size_t)row * 16384 + w * 64 + lane;
    unsigned long long* brow = bits + (size_t)row * 256 + w;
    int dpop = 0;
#pragma unroll 4
    for (int it = 0; it < 64; ++it) {
        int v = p[it * 256];
        unsigned long long m = __ballot(v != 0);
        if (lane == 0) {
            brow[it * 4] = m;
            dpop += __popcll(m);
        }
    }
    if (lane == 0) ds[w] = dpop;
    __syncthreads();
    if (t == 0) deg[row] = ds[0] + ds[1] + ds[2] + ds[3];
}

// ---------------- K0: transpose weight [512,256] f32 -> WT [512(n)][256(k)] bf16
__global__ __launch_bounds__(256) void k_transpose_w(const float* __restrict__ w,
                                                     uint16_t* __restrict__ wt) {
    int idx = blockIdx.x * 256 + threadIdx.x;   // 0..131071
    int n = idx >> 8;
    int k = idx & 255;
    int row = (n < 256) ? k : (256 + k);
    int col = (n < 256) ? n : (n - 256);
    uint32_t u = __float_as_uint(w[row * 256 + col]);
    u = (u + 0x7fffu + ((u >> 16) & 1u)) >> 16;
    wt[idx] = (uint16_t)u;
}

// ---------------- K1: small GEMM  [16384,256] @ [256,512] -> yT (cols 0..255) / z (cols 256..511)
__global__ __launch_bounds__(256) void k_small_gemm(const float* __restrict__ x,
                                                    const uint16_t* __restrict__ wt,
                                                    const float* __restrict__ bias,
                                                    uint16_t* __restrict__ yT,
                                                    float* __restrict__ z) {
    __shared__ uint16_t As[128 * 32];  // [m][k] bf16
    __shared__ uint16_t Bs[128 * 32];  // [n][k] bf16

    const int t  = threadIdx.x;
    const int ct = blockIdx.x;        // 0..3
    const int rt = blockIdx.y;        // 0..127
    const int m0 = rt * 128;
    const int n0 = ct * 128;

    const int lane = t & 63, w = t >> 6;
    const int wr = w >> 1, wc = w & 1;
    const int l15 = lane & 15, quad = lane >> 4;

    f32x4 acc[4][4] = {};

    float4 a_reg[4];
    uint4  b_reg[2];

#pragma unroll
    for (int i = 0; i < 4; ++i) {
        int f4 = t + 256 * i, row = f4 >> 3, c4 = f4 & 7;
        a_reg[i] = *(const float4*)(x + (m0 + row) * 256 + c4 * 4);
    }
#pragma unroll
    for (int i = 0; i < 2; ++i) {
        int u4 = t + 256 * i, n_l = u4 >> 2, part = u4 & 3;
        b_reg[i] = *(const uint4*)(wt + (n0 + n_l) * 256 + part * 8);
    }

    for (int kk = 0; kk < 8; ++kk) {
        __syncthreads();
#pragma unroll
        for (int i = 0; i < 4; ++i) {
            int f4 = t + 256 * i, row = f4 >> 3, c4 = f4 & 7;
            uint2 p;
            p.x = pack_bf16_rne(a_reg[i].x, a_reg[i].y);
            p.y = pack_bf16_rne(a_reg[i].z, a_reg[i].w);
            *(uint2*)(As + row * 32 + c4 * 4) = p;
        }
#pragma unroll
        for (int i = 0; i < 2; ++i) {
            int u4 = t + 256 * i, n_l = u4 >> 2, part = u4 & 3;
            *(uint4*)(Bs + n_l * 32 + part * 8) = b_reg[i];
        }
        if (kk < 7) {
            int k0 = (kk + 1) * 32;
#pragma unroll
            for (int i = 0; i < 4; ++i) {
                int f4 = t + 256 * i, row = f4 >> 3, c4 = f4 & 7;
                a_reg[i] = *(const float4*)(x + (m0 + row) * 256 + k0 + c4 * 4);
            }
#pragma unroll
            for (int i = 0; i < 2; ++i) {
                int u4 = t + 256 * i, n_l = u4 >> 2, part = u4 & 3;
                b_reg[i] = *(const uint4*)(wt + (n0 + n_l) * 256 + k0 + part * 8);
            }
        }
        __syncthreads();

        bf16x8 a_frag[4], b_frag[4];
#pragma unroll
        for (int fr = 0; fr < 4; ++fr)
            a_frag[fr] = *(const bf16x8*)(As + (wr * 64 + fr * 16 + l15) * 32 + quad * 8);
#pragma unroll
        for (int fc = 0; fc < 4; ++fc)
            b_frag[fc] = *(const bf16x8*)(Bs + (wc * 64 + fc * 16 + l15) * 32 + quad * 8);
#pragma unroll
        for (int fr = 0; fr < 4; ++fr)
#pragma unroll
            for (int fc = 0; fc < 4; ++fc)
                acc[fr][fc] = __builtin_amdgcn_mfma_f32_16x16x32_bf16(
                    a_frag[fr], b_frag[fc], acc[fr][fc], 0, 0, 0);
    }

    if (ct < 2) {
#pragma unroll
        for (int fr = 0; fr < 4; ++fr) {
            int m_base = m0 + wr * 64 + fr * 16 + quad * 4;
#pragma unroll
            for (int fc = 0; fc < 4; ++fc) {
                int n_g = n0 + wc * 64 + fc * 16 + l15;   // 0..255
                uint2 pp;
                pp.x = pack_bf16_rne(acc[fr][fc][0], acc[fr][fc][1]);
                pp.y = pack_bf16_rne(acc[fr][fc][2], acc[fr][fc][3]);
                *(uint2*)(yT + (size_t)n_g * 16384 + m_base) = pp;
            }
        }
    } else {
#pragma unroll
        for (int fr = 0; fr < 4; ++fr) {
            int m_base = m0 + wr * 64 + fr * 16 + quad * 4;
#pragma unroll
            for (int fc = 0; fc < 4; ++fc) {
                int n_g = (n0 - 256) + wc * 64 + fc * 16 + l15;  // 0..255
                float bv = bias[n_g];
#pragma unroll
                for (int r = 0; r < 4; ++r)
                    z[(size_t)(m_base + r) * 256 + n_g] = acc[fr][fc][r] + bv;
            }
        }
    }
}

// ---------------- K2 v8: partial[ky] = adj[:, ky-half] @ y[ky-half, :]
// grid (256 row-tiles, 2 k-halves), 512 threads (8 waves; wave = 32x64),
// BK=32, 256 iters. Tri-buffered LDS, raw s_barrier (lgkmcnt only),
// A expanded from bit words (L1-resident; 1 u32 per row per iter).
#define A_STRIDE 40                 // 64 rows x 40 halfwords (80B row, conflict-free)
#define A_SZ (64 * A_STRIDE)        // 2560 hw = 5120 B
#define B_SZ (256 * 32)             // 8192 hw = 16384 B, XOR-swizzled
#define KITER 256

#define BIG_STEP(CONS, PACK, ISSUE, KK)                                         \
  do {                                                                          \
    if ((KK) < KITER - 2) {                                                     \
      gload_lds16(pbg0, Bs##ISSUE + b_lb0); pbg0 += 32;                         \
      gload_lds16(pbg1, Bs##ISSUE + b_lb1); pbg1 += 32;                         \
    }                                                                           \
    uint32_t wNew = wB;                                                         \
    if ((KK) < KITER - 2) wNew = pw[(KK) + 2] >> a_sh;                          \
    /* drain stage KK+1's B (issued last step); keep this step's 3 in flight */ \
    asm volatile("s_waitcnt vmcnt(3)" ::: "memory");                            \
    if ((KK) < KITER - 1) {                                                     \
      uint2 pv;                                                                 \
      pv.x = (wB & 1u) * 0x3F80u + ((wB >> 1) & 1u) * 0x3F800000u;              \
      pv.y = ((wB >> 2) & 1u) * 0x3F80u + ((wB >> 3) & 1u) * 0x3F800000u;       \
      *(uint2*)&As##PACK[a_lds] = pv;                                           \
      wB = wNew;                                                                \
    }                                                                           \
    {                                                                           \
      bf16x8 af[2], bfr[4];                                                     \
      _Pragma("unroll") for (int fr = 0; fr < 2; ++fr) {                        \
        int row = wr * 32 + fr * 16 + l15;                                      \
        af[fr] = *(const bf16x8*)(As##CONS + row * A_STRIDE + quad * 8);        \
      }                                                                         \
      _Pragma("unroll") for (int fc = 0; fc < 4; ++fc) {                        \
        int n = wc * 64 + fc * 16 + l15;                                        \
        int cs = quad ^ ((n >> 1) & 3);                                         \
        bfr[fc] = *(const bf16x8*)(Bs##CONS + n * 32 + cs * 8);                 \
      }                                                                         \
      _Pragma("unroll") for (int fr = 0; fr < 2; ++fr)                          \
        _Pragma("unroll") for (int fc = 0; fc < 4; ++fc)                        \
          acc[fr][fc] = __builtin_amdgcn_mfma_f32_16x16x32_bf16(                \
              af[fr], bfr[fc], acc[fr][fc], 0, 0, 0);                           \
    }                                                                           \
    asm volatile("s_waitcnt lgkmcnt(0)\n\ts_barrier" ::: "memory");             \
  } while (0)

__global__ __launch_bounds__(512, 4) void k_big_gemm(const uint32_t* __restrict__ bits32,
                                                     const uint16_t* __restrict__ yT,
                                                     float* __restrict__ part) {
    __shared__ uint16_t As0[A_SZ], As1[A_SZ], As2[A_SZ];
    __shared__ uint16_t Bs0[B_SZ], Bs1[B_SZ], Bs2[B_SZ];   // total 63 KB

    const int t = threadIdx.x;
    const int m0 = blockIdx.x * 64;
    const int ky = blockIdx.y;                     // k-half
    const int kbase = ky * 8192;
    const int lane = t & 63, w = t >> 6;
    const int wr = w >> 2, wc = w & 3;             // wave: 2 row frags, 4 col frags
    const int l15 = lane & 15, quad = lane >> 4;

    f32x4 acc[2][4] = {};

    // A expansion: thread owns row a_n, nibble a_c4 of the per-iter u32 word.
    const int a_n = t >> 3, a_c4 = t & 7;
    const int a_sh = a_c4 * 4;
    const uint32_t* pw = bits32 + (size_t)(m0 + a_n) * 512 + ky * 256;
    const int a_lds = a_n * A_STRIDE + a_c4 * 4;

    // B staging: 256 rows x 32 bf16 / iter = 1024 16B slots, 2 gload_lds/thread
    const uint16_t *pbg0, *pbg1;
    int b_lb0, b_lb1;
    {
        int base0 = (w * 2 + 0) * 64, base1 = (w * 2 + 1) * 64;
        int s0 = base0 + lane, s1 = base1 + lane;
        int bn0 = s0 >> 2, bn1 = s1 >> 2;
        int bc0 = (s0 & 3) ^ ((bn0 >> 1) & 3);
        int bc1 = (s1 & 3) ^ ((bn1 >> 1) & 3);
        pbg0 = yT + (size_t)bn0 * 16384 + kbase + bc0 * 8;
        pbg1 = yT + (size_t)bn1 * 16384 + kbase + bc1 * 8;
        b_lb0 = base0 * 8;
        b_lb1 = base1 * 8;
    }

    // ---- prologue: B(0)->Bs0, B(1)->Bs1, words 0/1, pack stage 0
    gload_lds16(pbg0, Bs0 + b_lb0); pbg0 += 32;
    gload_lds16(pbg1, Bs0 + b_lb1); pbg1 += 32;
    uint32_t w0 = pw[0] >> a_sh;
    gload_lds16(pbg0, Bs1 + b_lb0); pbg0 += 32;
    gload_lds16(pbg1, Bs1 + b_lb1); pbg1 += 32;
    uint32_t wB = pw[1] >> a_sh;
    {
        uint2 pv;
        pv.x = (w0 & 1u) * 0x3F80u + ((w0 >> 1) & 1u) * 0x3F800000u;
        pv.y = ((w0 >> 2) & 1u) * 0x3F80u + ((w0 >> 3) & 1u) * 0x3F800000u;
        *(uint2*)&As0[a_lds] = pv;
    }
    asm volatile("s_waitcnt vmcnt(3)" ::: "memory");   // B(0) complete
    asm volatile("s_waitcnt lgkmcnt(0)\n\ts_barrier" ::: "memory");

    // ---- main loop: 85 triples (kk = 0..254), then tail step kk = 255
    for (int kk = 0; kk < KITER - 1; kk += 3) {
        BIG_STEP(0, 1, 2, kk);
        BIG_STEP(1, 2, 0, kk + 1);
        BIG_STEP(2, 0, 1, kk + 2);
    }
    BIG_STEP(0, 1, 2, KITER - 1);   // 255 % 3 == 0

    // partial C (C/D layout: col=lane&15, row=quad*4+reg)
    float* pc = part + (size_t)ky * 16384 * 256;
#pragma unroll
    for (int fr = 0; fr < 2; ++fr) {
#pragma unroll
        for (int r = 0; r < 4; ++r) {
            int m_l = wr * 32 + fr * 16 + quad * 4 + r;
            size_t mrow = (size_t)(m0 + m_l) * 256;
#pragma unroll
            for (int fc = 0; fc < 4; ++fc) {
                int n_g = wc * 64 + fc * 16 + l15;
                pc[mrow + n_g] = acc[fr][fc][r];
            }
        }
    }
}

// ---------------- K3: out = (p0+p1)/deg + z
__global__ __launch_bounds__(256) void k_reduce(const float* __restrict__ part,
                                                const int* __restrict__ deg,
                                                const float* __restrict__ z,
                                                float* __restrict__ out) {
    int i4 = blockIdx.x * 256 + threadIdx.x;       // float4 index, 64 per row
    int m = i4 >> 6;
    float4 p0 = ((const float4*)part)[i4];
    float4 p1 = ((const float4*)part)[i4 + 16384 * 64];
    float4 zz = ((const float4*)z)[i4];
    float inv = 1.0f / (float)deg[m];
    float4 o;
    o.x = (p0.x + p1.x) * inv + zz.x;
    o.y = (p0.y + p1.y) * inv + zz.y;
    o.z = (p0.z + p1.z) * inv + zz.z;
    o.w = (p0.w + p1.w) * inv + zz.w;
    ((float4*)out)[i4] = o;
}

extern "C" void kernel_launch(void* const* d_in, const int* in_sizes, int n_in,
                              void* d_out, int out_size, void* d_ws, size_t ws_size,
                              hipStream_t stream) {
    const float* x      = (const float*)d_in[0];
    const int*   adj    = (const int*)d_in[1];
    const float* weight = (const float*)d_in[2];
    const float* bias   = (const float*)d_in[3];
    float* out = (float*)d_out;

    // ws: WT 256KB | yT 8MB | z 16MB | part 32MB | deg 64KB | bits 32MB (~90MB)
    char* wsb = (char*)d_ws;
    uint16_t* wt   = (uint16_t*)(wsb);
    uint16_t* yT   = (uint16_t*)(wsb + 262144);
    float*    z    = (float*)(wsb + 262144 + 8388608);
    float*    partb= (float*)(wsb + 262144 + 8388608 + 16777216);
    int*      deg  = (int*)(wsb + 262144 + 8388608 + 16777216 + 33554432);
    unsigned long long* bits =
        (unsigned long long*)(wsb + 262144 + 8388608 + 16777216 + 33554432 + 65536);

    k_bitpack<<<16384, 256, 0, stream>>>(adj, bits, deg);
    k_transpose_w<<<512, 256, 0, stream>>>(weight, wt);
    k_small_gemm<<<dim3(4, 128), 256, 0, stream>>>(x, wt, bias, yT, z);
    k_big_gemm<<<dim3(256, 2), 512, 0, stream>>>((const uint32_t*)bits, yT, partb);
    k_reduce<<<4096, 256, 0, stream>>>(partb, deg, z, out);
}

// Round 9
// 1429.540 us; speedup vs baseline: 1.1636x; 1.1636x over previous
//
#include <hip/hip_runtime.h>
#include <hip/hip_bf16.h>
#include <stdint.h>

// GraphSAGE layer, N=16384, F_IN=F_OUT=256.
// out = (adj@ (x@W1))/deg + x@W2 + bias
//   K0: WT[n][k] (bf16)  = transpose of [W1|W2]
//   K1: yTt[j/32][n][32] (bf16, K-TILED) = (x@W1)^T ; z[m][n] = x@W2 + bias
//   K2 v9: split-K 2, 8 waves of 32x64, BK=32, TRI-buffered LDS,
//          ALL-REGISTER staging (global_load -> regs -> ds_write), raw
//          s_barrier (lgkmcnt(0) only). Compiler inserts fine-grained
//          vmcnt(N) for the reg->LDS writes => loads stay in flight across
//          barriers (AITER pattern). A loaded 3 steps ahead (HBM slack),
//          B 2 steps ahead (L2 slack). LDS strides padded to 36 hw
//          (bank-balanced for both reads and writes).
//   K3: out = (p0+p1)/(d0+d1) + z

typedef short bf16x8 __attribute__((ext_vector_type(8)));
typedef float f32x4  __attribute__((ext_vector_type(4)));

__device__ __forceinline__ uint32_t pack_bf16_rne(float lo, float hi) {
    uint32_t ul = __float_as_uint(lo);
    uint32_t uh = __float_as_uint(hi);
    ul = (ul + 0x7fffu + ((ul >> 16) & 1u)) >> 16;
    uh = (uh + 0x7fffu + ((uh >> 16) & 1u)) >> 16;
    return ul | (uh << 16);
}

// ---------------- K0: transpose weight [512,256] f32 -> WT [512(n)][256(k)] bf16
__global__ __launch_bounds__(256) void k_transpose_w(const float* __restrict__ w,
                                                     uint16_t* __restrict__ wt) {
    int idx = blockIdx.x * 256 + threadIdx.x;   // 0..131071
    int n = idx >> 8;
    int k = idx & 255;
    int row = (n < 256) ? k : (256 + k);
    int col = (n < 256) ? n : (n - 256);
    uint32_t u = __float_as_uint(w[row * 256 + col]);
    u = (u + 0x7fffu + ((u >> 16) & 1u)) >> 16;
    wt[idx] = (uint16_t)u;
}

// ---------------- K1: small GEMM  [16384,256] @ [256,512]
// -> yTt (K-tiled transpose, cols 0..255) / z (cols 256..511)
__global__ __launch_bounds__(256) void k_small_gemm(const float* __restrict__ x,
                                                    const uint16_t* __restrict__ wt,
                                                    const float* __restrict__ bias,
                                                    uint16_t* __restrict__ yTt,
                                                    float* __restrict__ z) {
    __shared__ uint16_t As[128 * 32];  // [m][k] bf16
    __shared__ uint16_t Bs[128 * 32];  // [n][k] bf16

    const int t  = threadIdx.x;
    const int ct = blockIdx.x;        // 0..3
    const int rt = blockIdx.y;        // 0..127
    const int m0 = rt * 128;
    const int n0 = ct * 128;

    const int lane = t & 63, w = t >> 6;
    const int wr = w >> 1, wc = w & 1;
    const int l15 = lane & 15, quad = lane >> 4;

    f32x4 acc[4][4] = {};

    float4 a_reg[4];
    uint4  b_reg[2];

#pragma unroll
    for (int i = 0; i < 4; ++i) {
        int f4 = t + 256 * i, row = f4 >> 3, c4 = f4 & 7;
        a_reg[i] = *(const float4*)(x + (m0 + row) * 256 + c4 * 4);
    }
#pragma unroll
    for (int i = 0; i < 2; ++i) {
        int u4 = t + 256 * i, n_l = u4 >> 2, part = u4 & 3;
        b_reg[i] = *(const uint4*)(wt + (n0 + n_l) * 256 + part * 8);
    }

    for (int kk = 0; kk < 8; ++kk) {
        __syncthreads();
#pragma unroll
        for (int i = 0; i < 4; ++i) {
            int f4 = t + 256 * i, row = f4 >> 3, c4 = f4 & 7;
            uint2 p;
            p.x = pack_bf16_rne(a_reg[i].x, a_reg[i].y);
            p.y = pack_bf16_rne(a_reg[i].z, a_reg[i].w);
            *(uint2*)(As + row * 32 + c4 * 4) = p;
        }
#pragma unroll
        for (int i = 0; i < 2; ++i) {
            int u4 = t + 256 * i, n_l = u4 >> 2, part = u4 & 3;
            *(uint4*)(Bs + n_l * 32 + part * 8) = b_reg[i];
        }
        if (kk < 7) {
            int k0 = (kk + 1) * 32;
#pragma unroll
            for (int i = 0; i < 4; ++i) {
                int f4 = t + 256 * i, row = f4 >> 3, c4 = f4 & 7;
                a_reg[i] = *(const float4*)(x + (m0 + row) * 256 + k0 + c4 * 4);
            }
#pragma unroll
            for (int i = 0; i < 2; ++i) {
                int u4 = t + 256 * i, n_l = u4 >> 2, part = u4 & 3;
                b_reg[i] = *(const uint4*)(wt + (n0 + n_l) * 256 + k0 + part * 8);
            }
        }
        __syncthreads();

        bf16x8 a_frag[4], b_frag[4];
#pragma unroll
        for (int fr = 0; fr < 4; ++fr)
            a_frag[fr] = *(const bf16x8*)(As + (wr * 64 + fr * 16 + l15) * 32 + quad * 8);
#pragma unroll
        for (int fc = 0; fc < 4; ++fc)
            b_frag[fc] = *(const bf16x8*)(Bs + (wc * 64 + fc * 16 + l15) * 32 + quad * 8);
#pragma unroll
        for (int fr = 0; fr < 4; ++fr)
#pragma unroll
            for (int fc = 0; fc < 4; ++fc)
                acc[fr][fc] = __builtin_amdgcn_mfma_f32_16x16x32_bf16(
                    a_frag[fr], b_frag[fc], acc[fr][fc], 0, 0, 0);
    }

    if (ct < 2) {
        // y^T K-tiled: yTt[(m>>5)][n][32] + (m&31); lane's 4 regs = 4
        // consecutive m inside one 32-tile (m_base%32 <= 28) -> one uint2
#pragma unroll
        for (int fr = 0; fr < 4; ++fr) {
            int m_base = m0 + wr * 64 + fr * 16 + quad * 4;
#pragma unroll
            for (int fc = 0; fc < 4; ++fc) {
                int n_g = n0 + wc * 64 + fc * 16 + l15;   // 0..255
                uint2 pp;
                pp.x = pack_bf16_rne(acc[fr][fc][0], acc[fr][fc][1]);
                pp.y = pack_bf16_rne(acc[fr][fc][2], acc[fr][fc][3]);
                *(uint2*)(yTt + (size_t)(m_base >> 5) * 8192 + n_g * 32 + (m_base & 31)) = pp;
            }
        }
    } else {
#pragma unroll
        for (int fr = 0; fr < 4; ++fr) {
            int m_base = m0 + wr * 64 + fr * 16 + quad * 4;
#pragma unroll
            for (int fc = 0; fc < 4; ++fc) {
                int n_g = (n0 - 256) + wc * 64 + fc * 16 + l15;  // 0..255
                float bv = bias[n_g];
#pragma unroll
                for (int r = 0; r < 4; ++r)
                    z[(size_t)(m_base + r) * 256 + n_g] = acc[fr][fc][r] + bv;
            }
        }
    }
}

// ---------------- K2 v9
#define A_STRIDE 36                 // 64 rows x 36 hw (32 data + 4 pad) — bank-balanced
#define B_STRIDE 36                 // 256 rows x 36 hw
#define A_SZ (64 * A_STRIDE)        // 2304 hw = 4.5 KB
#define B_SZ (256 * B_STRIDE)       // 9216 hw = 18 KB
#define KITER 256

// One step. RD/WR: compile-time LDS buffer ids. KK: step index (runtime ok).
#define STEP(ARD, BRD, AWR, BWR, KK)                                            \
  do {                                                                          \
    if ((KK) < KITER - 2) {  /* B(KK+2) regs */                                 \
      bN0 = *(const uint4*)(pB);                                                \
      bN1 = *(const uint4*)(pB + 4096);                                         \
      pB += 8192;                                                               \
    }                                                                           \
    if ((KK) < KITER - 3) {  /* A(KK+3) regs */                                 \
      aN = pa4[0]; pa4 += 8;                                                    \
    }                                                                           \
    if ((KK) < KITER - 1) {  /* stage KK+1 -> LDS */                            \
      degp += aQ0.x + aQ0.y + aQ0.z + aQ0.w;                                    \
      uint2 pv;                                                                 \
      pv.x = (uint32_t)(aQ0.x | (aQ0.y << 16)) * 0x3F80u;                       \
      pv.y = (uint32_t)(aQ0.z | (aQ0.w << 16)) * 0x3F80u;                       \
      *(uint2*)&As##AWR[a_lds] = pv;                                            \
      *(uint4*)&Bs##BWR[b_lds0] = bC0;                                          \
      *(uint4*)&Bs##BWR[b_lds1] = bC1;                                          \
    }                                                                           \
    {                                                                           \
      bf16x8 af[2], bfr[4];                                                     \
      _Pragma("unroll") for (int fr = 0; fr < 2; ++fr) {                        \
        int row = wr * 32 + fr * 16 + l15;                                      \
        af[fr] = *(const bf16x8*)(As##ARD + row * A_STRIDE + quad * 8);         \
      }                                                                         \
      _Pragma("unroll") for (int fc = 0; fc < 4; ++fc) {                        \
        int n = wc * 64 + fc * 16 + l15;                                        \
        bfr[fc] = *(const bf16x8*)(Bs##BRD + n * B_STRIDE + quad * 8);          \
      }                                                                         \
      _Pragma("unroll") for (int fr = 0; fr < 2; ++fr)                          \
        _Pragma("unroll") for (int fc = 0; fc < 4; ++fc)                        \
          acc[fr][fc] = __builtin_amdgcn_mfma_f32_16x16x32_bf16(                \
              af[fr], bfr[fc], acc[fr][fc], 0, 0, 0);                           \
    }                                                                           \
    aQ0 = aQ1; aQ1 = aQ2; aQ2 = aN;                                             \
    bC0 = bN0; bC1 = bN1;                                                       \
    asm volatile("s_waitcnt lgkmcnt(0)\n\ts_barrier" ::: "memory");             \
  } while (0)

__global__ __launch_bounds__(512, 4) void k_big_gemm(const int* __restrict__ adj,
                                                     const uint16_t* __restrict__ yTt,
                                                     float* __restrict__ part,
                                                     int* __restrict__ degw) {
    __shared__ uint16_t As0[A_SZ], As1[A_SZ], As2[A_SZ];   // 13.5 KB
    __shared__ uint16_t Bs0[B_SZ], Bs1[B_SZ], Bs2[B_SZ];   // 54 KB

    const int t = threadIdx.x;
    const int m0 = blockIdx.x * 64;
    const int ky = blockIdx.y;                     // k-half
    const int lane = t & 63, w = t >> 6;
    const int wr = w >> 2, wc = w & 3;             // wave: 2 row frags, 4 col frags
    const int l15 = lane & 15, quad = lane >> 4;

    f32x4 acc[2][4] = {};

    // A: 64 rows x 32 ints / stage = 512 int4, one per thread
    const int a_n = t >> 3, a_c4 = t & 7;
    const int4* pa4 = (const int4*)(adj + (size_t)(m0 + a_n) * 16384 + ky * 8192) + a_c4;
    const int a_lds = a_n * A_STRIDE + a_c4 * 4;

    // B: stage kk = yTt tile (ky*256 + kk): contiguous 16 KB; 2 uint4/thread
    const uint16_t* pB = yTt + (size_t)(ky * 256) * 8192 + t * 8;
    const int b_s0 = t, b_s1 = t + 512;            // slots
    const int b_lds0 = (b_s0 >> 2) * B_STRIDE + (b_s0 & 3) * 8;
    const int b_lds1 = (b_s1 >> 2) * B_STRIDE + (b_s1 & 3) * 8;

    // ---- prologue: load A(0..2), B(0..1); stage 0 -> LDS buf 0
    int4 a0 = pa4[0];
    int4 aQ0 = pa4[8];            // A(1)
    int4 aQ1 = pa4[16];           // A(2)
    int4 aQ2;                     // A(3) loaded in step 0
    int4 aN = aQ1;
    pa4 += 24;
    uint4 b00 = *(const uint4*)(pB);
    uint4 b01 = *(const uint4*)(pB + 4096);
    pB += 8192;
    uint4 bC0 = *(const uint4*)(pB);          // B(1)
    uint4 bC1 = *(const uint4*)(pB + 4096);
    pB += 8192;
    uint4 bN0 = bC0, bN1 = bC1;

    int degp = a0.x + a0.y + a0.z + a0.w;
    {
        uint2 pv;
        pv.x = (uint32_t)(a0.x | (a0.y << 16)) * 0x3F80u;
        pv.y = (uint32_t)(a0.z | (a0.w << 16)) * 0x3F80u;
        *(uint2*)&As0[a_lds] = pv;
        *(uint4*)&Bs0[b_lds0] = b00;
        *(uint4*)&Bs0[b_lds1] = b01;
    }
    asm volatile("s_waitcnt lgkmcnt(0)\n\ts_barrier" ::: "memory");

    // ---- main loop: 84 triples = steps 0..251 (all guards true), tail 252..255
    for (int kk = 0; kk < KITER - 4; kk += 3) {
        STEP(0, 0, 1, 1, kk);
        STEP(1, 1, 2, 2, kk + 1);
        STEP(2, 2, 0, 0, kk + 2);
    }
    STEP(0, 0, 1, 1, 252);
    STEP(1, 1, 2, 2, 253);
    STEP(2, 2, 0, 0, 254);
    STEP(0, 0, 1, 1, 255);

    // partial deg: row a_n owned by 8 consecutive lanes
    degp += __shfl_down(degp, 4);
    degp += __shfl_down(degp, 2);
    degp += __shfl_down(degp, 1);
    if ((t & 7) == 0) degw[ky * 16384 + m0 + a_n] = degp;

    // partial C (C/D layout: col=lane&15, row=quad*4+reg)
    float* pc = part + (size_t)ky * 16384 * 256;
#pragma unroll
    for (int fr = 0; fr < 2; ++fr) {
#pragma unroll
        for (int r = 0; r < 4; ++r) {
            int m_l = wr * 32 + fr * 16 + quad * 4 + r;
            size_t mrow = (size_t)(m0 + m_l) * 256;
#pragma unroll
            for (int fc = 0; fc < 4; ++fc) {
                int n_g = wc * 64 + fc * 16 + l15;
                pc[mrow + n_g] = acc[fr][fc][r];
            }
        }
    }
}

// ---------------- K3: out = (p0+p1)/(d0+d1) + z
__global__ __launch_bounds__(256) void k_reduce(const float* __restrict__ part,
                                                const int* __restrict__ degw,
                                                const float* __restrict__ z,
                                                float* __restrict__ out) {
    int i4 = blockIdx.x * 256 + threadIdx.x;       // float4 index, 64 per row
    int m = i4 >> 6;
    float4 p0 = ((const float4*)part)[i4];
    float4 p1 = ((const float4*)part)[i4 + 16384 * 64];
    float4 zz = ((const float4*)z)[i4];
    float inv = 1.0f / (float)(degw[m] + degw[16384 + m]);
    float4 o;
    o.x = (p0.x + p1.x) * inv + zz.x;
    o.y = (p0.y + p1.y) * inv + zz.y;
    o.z = (p0.z + p1.z) * inv + zz.z;
    o.w = (p0.w + p1.w) * inv + zz.w;
    ((float4*)out)[i4] = o;
}

extern "C" void kernel_launch(void* const* d_in, const int* in_sizes, int n_in,
                              void* d_out, int out_size, void* d_ws, size_t ws_size,
                              hipStream_t stream) {
    const float* x      = (const float*)d_in[0];
    const int*   adj    = (const int*)d_in[1];
    const float* weight = (const float*)d_in[2];
    const float* bias   = (const float*)d_in[3];
    float* out = (float*)d_out;

    // ws: WT 256KB | yTt 8MB | z 16MB | part 32MB | degw 128KB
    char* wsb = (char*)d_ws;
    uint16_t* wt   = (uint16_t*)(wsb);
    uint16_t* yTt  = (uint16_t*)(wsb + 262144);
    float*    z    = (float*)(wsb + 262144 + 8388608);
    float*    partb= (float*)(wsb + 262144 + 8388608 + 16777216);
    int*      degw = (int*)(wsb + 262144 + 8388608 + 16777216 + 33554432);

    k_transpose_w<<<512, 256, 0, stream>>>(weight, wt);
    k_small_gemm<<<dim3(4, 128), 256, 0, stream>>>(x, wt, bias, yTt, z);
    k_big_gemm<<<dim3(256, 2), 512, 0, stream>>>(adj, yTt, partb, degw);
    k_reduce<<<4096, 256, 0, stream>>>(partb, degw, z, out);
}